// Round 20
// baseline (130.112 us; speedup 1.0000x reference)
//
#include <hip/hip_runtime.h>
#include <hip/hip_bf16.h>
#include <stdint.h>

// MHA: B=2, S=2048, D=1024, H=16, Dh=64.
// cvt_all: fp32->bf16 for inputs+weights (one launch).
// proj GEMM: BK=32 2-phase dbuf + T1 XCD-chunk swizzle (retry at 3 blocks/CU).
// out GEMM (R13-exact): BK=32 2-phase dbuf + T1.
// attn: 8 waves x 16 q-rows, 3-buffer counted-vmcnt staging, permuted-K
//       swapped QK^T (P lane-local, no LDS roundtrip), no-max exp2 softmax,
//       row-sum via ones-MFMA (no serial VALU adds, no end shuffles).

typedef unsigned short u16;
typedef __attribute__((ext_vector_type(8))) short bf16x8;   // 8 bf16 = 4 VGPR
typedef __attribute__((ext_vector_type(4))) float f32x4;

#define MFMA16 __builtin_amdgcn_mfma_f32_16x16x32_bf16
#define AS1 __attribute__((address_space(1)))
#define AS3 __attribute__((address_space(3)))

#define GM 4096
#define GN 1024
#define GK 1024
#define S_LEN 2048
#define NH 16
#define DH 64
#define KVBLK 64

__device__ __forceinline__ u16 f2bf(float f) {
    union { float f; uint32_t u; } v; v.f = f;
    return (u16)((v.u + 0x7fffu + ((v.u >> 16) & 1u)) >> 16);
}

__device__ __forceinline__ uint32_t pack_bf16(float lo, float hi) {
    float2 t; t.x = lo; t.y = hi;
    __hip_bfloat162 h = __float22bfloat162_rn(t);
    return *(uint32_t*)&h;
}

// ---------------- fused fp32 -> bf16 convert for all 7 tensors + bq scale ----------------
__global__ __launch_bounds__(256) void cvt_all_kernel(
        const float* __restrict__ q, const float* __restrict__ k, const float* __restrict__ v,
        const float* __restrict__ Wq, const float* __restrict__ Wk,
        const float* __restrict__ Wv, const float* __restrict__ Wo,
        const float* __restrict__ bq,
        u16* __restrict__ qbf, u16* __restrict__ kbf, u16* __restrict__ vbf,
        u16* __restrict__ Wqb, u16* __restrict__ Wkb, u16* __restrict__ Wvb,
        u16* __restrict__ Wob, float* __restrict__ bqs, float qscale) {
    int bid = blockIdx.x;
    if (bid >= 8192) {                   // bq scale (fp32 passthrough)
        int i = (bid - 8192) * 256 + (int)threadIdx.x;
        if (i < GN) bqs[i] = bq[i] * qscale;
        return;
    }
    const float* src; u16* dst; float scale = 1.f; int off;
    if      (bid < 2048) { src = q;  dst = qbf; off = bid; }
    else if (bid < 4096) { src = k;  dst = kbf; off = bid - 2048; }
    else if (bid < 6144) { src = v;  dst = vbf; off = bid - 4096; }
    else if (bid < 6656) { src = Wq; dst = Wqb; off = bid - 6144; scale = qscale; }
    else if (bid < 7168) { src = Wk; dst = Wkb; off = bid - 6656; }
    else if (bid < 7680) { src = Wv; dst = Wvb; off = bid - 7168; }
    else                 { src = Wo; dst = Wob; off = bid - 7680; }
    size_t i = (size_t)off * 256 + threadIdx.x;
    const f32x4* s = (const f32x4*)src + i * 2;
    f32x4 a = s[0], b = s[1];
    union { bf16x8 v8; u16 u[8]; } o;
    o.u[0] = f2bf(a[0] * scale); o.u[1] = f2bf(a[1] * scale);
    o.u[2] = f2bf(a[2] * scale); o.u[3] = f2bf(a[3] * scale);
    o.u[4] = f2bf(b[0] * scale); o.u[5] = f2bf(b[1] * scale);
    o.u[6] = f2bf(b[2] * scale); o.u[7] = f2bf(b[3] * scale);
    *(bf16x8*)(dst + i * 8) = o.v8;
}

// ---------------- 128x128-tile bf16 GEMM core (R13-exact), templated K-depth ----------------
template<int BK>
__device__ __forceinline__ void gemm_core(const u16* __restrict__ A,
                                          const u16* __restrict__ W,
                                          const float* __restrict__ bias,
                                          void* __restrict__ Cout, int mode,
                                          u16* As, u16* Bs,
                                          int mbase, int nbase) {
    const int t  = threadIdx.x;
    const int l  = t & 63;
    const int w  = t >> 6;
    const int wr = w >> 1, wc = w & 1;           // 2x2 wave grid
    const int cl = l & 15, g = l >> 4;
    constexpr int CPR  = BK / 8;                 // 16B chunks per row
    constexpr int NCH  = 128 * CPR / 256;        // chunk-loop count per tensor
    constexpr int TE   = 128 * BK;               // tile elems (u16)

    f32x4 acc[4][4];
    f32x4 zero = {0.f, 0.f, 0.f, 0.f};
    #pragma unroll
    for (int i = 0; i < 4; ++i)
        #pragma unroll
        for (int j = 0; j < 4; ++j) acc[i][j] = zero;

    auto skey = [](int row) -> int {
        if constexpr (BK == 64) return row & 7;
        else                    return (row >> 1) & 3;
    };

    auto stage = [&](int buf, int kt) {
        #pragma unroll
        for (int r = 0; r < NCH; ++r) {
            int c = r * 256 + t;
            int row = c / CPR;
            int c8 = (c % CPR) ^ skey(row);
            __builtin_amdgcn_global_load_lds(
                (const AS1 void*)(A + (size_t)(mbase + row) * GK + kt + c8 * 8),
                (AS3 void*)(As + buf * TE + c * 8), 16, 0, 0);
            __builtin_amdgcn_global_load_lds(
                (const AS1 void*)(W + (size_t)(nbase + row) * GK + kt + c8 * 8),
                (AS3 void*)(Bs + buf * TE + c * 8), 16, 0, 0);
        }
    };

    stage(0, 0);
    __syncthreads();

    int cur = 0;
    for (int kt = 0; kt < GK; kt += BK) {
        if (kt + BK < GK) stage(cur ^ 1, kt + BK);   // prefetch next tile

        const u16* Asb = As + cur * TE;
        const u16* Bsb = Bs + cur * TE;
        #pragma unroll
        for (int ks = 0; ks < BK / 32; ++ks) {
            bf16x8 af[4], bfr[4];
            #pragma unroll
            for (int mi = 0; mi < 4; ++mi) {
                int row = wr * 64 + mi * 16 + cl;
                af[mi] = *(const bf16x8*)&Asb[row * BK + ((ks * 4 + g) ^ skey(row)) * 8];
            }
            #pragma unroll
            for (int nj = 0; nj < 4; ++nj) {
                int row = wc * 64 + nj * 16 + cl;
                bfr[nj] = *(const bf16x8*)&Bsb[row * BK + ((ks * 4 + g) ^ skey(row)) * 8];
            }
            #pragma unroll
            for (int mi = 0; mi < 4; ++mi)
                #pragma unroll
                for (int nj = 0; nj < 4; ++nj)
                    acc[mi][nj] = MFMA16(af[mi], bfr[nj], acc[mi][nj], 0, 0, 0);
        }
        __syncthreads();
        cur ^= 1;
    }

    // epilogue: C/D layout col = lane&15, row = (lane>>4)*4 + reg (m89-verified)
    #pragma unroll
    for (int mi = 0; mi < 4; ++mi) {
        #pragma unroll
        for (int nj = 0; nj < 4; ++nj) {
            int n = nbase + wc * 64 + nj * 16 + cl;
            float bv = bias[n];
            #pragma unroll
            for (int r = 0; r < 4; ++r) {
                int m = mbase + wr * 64 + mi * 16 + g * 4 + r;
                float vv = acc[mi][nj][r] + bv;
                if (mode == 2) {
                    ((float*)Cout)[(size_t)m * GN + n] = vv;
                } else {
                    int b = m >> 11, s = m & 2047;
                    int hh = n >> 6, dh = n & 63;
                    if (mode == 0)       // [B,H,S,Dh]
                        ((u16*)Cout)[(((size_t)(b * NH + hh)) * S_LEN + s) * DH + dh] = f2bf(vv);
                    else                 // [B,H,Dh,S]  (V transposed)
                        ((u16*)Cout)[(((size_t)(b * NH + hh)) * DH + dh) * S_LEN + s] = f2bf(vv);
                }
            }
        }
    }
}

// T1 XCD-chunk swizzle: 768 blocks (%8==0), cpx=96; x fastest (W L2-hot).
__global__ __launch_bounds__(256) void proj_gemm(
        const u16* __restrict__ qbf, const u16* __restrict__ kbf, const u16* __restrict__ vbf,
        const u16* __restrict__ Wqb, const u16* __restrict__ Wkb, const u16* __restrict__ Wvb,
        const float* __restrict__ bq, const float* __restrict__ bk, const float* __restrict__ bv,
        u16* __restrict__ Qb, u16* __restrict__ Kb, u16* __restrict__ Vtb) {
    __shared__ u16 As[2 * 128 * 32];     // 16KB
    __shared__ u16 Bs[2 * 128 * 32];     // 16KB  -> 32KB total, 3 blocks/CU
    int bid = blockIdx.x;
    int lid = (bid & 7) * 96 + (bid >> 3);
    int x = lid & 7;                     // n-tile (cycles fastest)
    int wv = lid >> 3;                   // 0..95 = z*32 + y
    int z = wv >> 5, y = wv & 31;
    const u16* A   = (z == 0) ? qbf : (z == 1) ? kbf : vbf;
    const u16* W   = (z == 0) ? Wqb : (z == 1) ? Wkb : Wvb;
    const float* b = (z == 0) ? bq  : (z == 1) ? bk  : bv;
    u16* C         = (z == 0) ? Qb  : (z == 1) ? Kb  : Vtb;
    gemm_core<32>(A, W, b, (void*)C, (z == 2) ? 1 : 0, As, Bs, y * 128, x * 128);
}

__global__ __launch_bounds__(256) void out_gemm(const u16* __restrict__ A,
                                                const u16* __restrict__ W,
                                                const float* __restrict__ bias,
                                                float* __restrict__ C) {
    __shared__ u16 As[2 * 128 * 32];
    __shared__ u16 Bs[2 * 128 * 32];
    int bid = blockIdx.x;                        // 256 blocks, 256%8==0
    int lid = (bid & 7) * 32 + (bid >> 3);
    int x = lid & 7, y = lid >> 3;
    gemm_core<32>(A, W, bias, (void*)C, 2, As, Bs, y * 128, x * 128);
}

// ---------------- flash attention: permuted-K swapped QK^T, ones-MFMA row-sum ----------------
// Q (pre-scaled by 0.125*log2e), K: [B*H, S, 64] bf16; Vt: [B*H, 64, S] bf16.
// O: [B, S, 1024] bf16.  8 waves x 16 q-rows, 3 LDS buffers, 2-deep prefetch,
// counted vmcnt(2). MFMA j's A-operand reads K row f(j,i) = (j&1)*32 +
// (i>>2)*8 + (j>>1)*4 + (i&3), so lane (cl,g)'s 16 logits are EXACTLY its PV
// A-fragment. Row-sum: sacc = mfma(pf, ones, sacc) -> sacc[r] = rowsum[q=g*4+r]
// (replicated over cl) — no serial adds, no end shuffles, denominator uses
// the same bf16-rounded p as the numerator (exactly-normalized weights).
__global__ __launch_bounds__(512, 4) void attn_kernel(const u16* __restrict__ Q,
                                                      const u16* __restrict__ Kb,
                                                      const u16* __restrict__ Vt,
                                                      u16* __restrict__ O) {
    __shared__ u16 Ks[3][KVBLK * 64];            // 8KB each
    __shared__ u16 Vs[3][KVBLK * 64];            // 8KB each  -> 48KB total

    const int t = threadIdx.x, l = t & 63, w = t >> 6;
    const int cl = l & 15, g = l >> 4;
    const int bh = blockIdx.x;                   // 0..31
    const int b = bh >> 4, h = bh & 15;
    const int qw = blockIdx.y * 128 + w * 16;    // this wave's q-row base

    const u16* Qp = Q  + ((size_t)bh * S_LEN + qw) * DH;
    const u16* Kp = Kb + (size_t)bh * S_LEN * DH;
    const u16* Vp = Vt + (size_t)bh * DH * S_LEN;

    // Q fragment (q = cl, d = (lane>>4)*8+e) — MFMA B-operand of swapped QK^T
    bf16x8 qf0 = *(const bf16x8*)(Qp + (size_t)cl * DH + g * 8);
    bf16x8 qf1 = *(const bf16x8*)(Qp + (size_t)cl * DH + 32 + g * 8);

    f32x4 oacc[4];
    f32x4 zero = {0.f, 0.f, 0.f, 0.f};
    #pragma unroll
    for (int tt = 0; tt < 4; ++tt) oacc[tt] = zero;
    f32x4 sacc = zero;                           // row-sum accumulator (ones-MFMA)

    bf16x8 ones;
    #pragma unroll
    for (int e = 0; e < 8; ++e) ones[e] = (short)0x3F80;   // bf16 1.0

    // read-side swizzle keys (storage key(row)=(row&3)|((row>>3)&1)<<2)
    const int kx = (cl & 3) | (((cl >> 2) & 1) << 2);
    const int vx = (cl & 3) | (((cl >> 3) & 1) << 2);

    // staging geometry: 512 threads x one 16B chunk per tensor.
    const int srow = t >> 3;
    const int sc8  = (t & 7) ^ ((srow & 3) | (((srow >> 3) & 1) << 2));
    const u16* Kg = Kp + (size_t)srow * DH + sc8 * 8;
    const u16* Vg = Vp + (size_t)srow * S_LEN + sc8 * 8;

    #define STAGE(buf, kvoff)                                                            \
        do {                                                                             \
            __builtin_amdgcn_global_load_lds(                                            \
                (const AS1 void*)(Kg + (size_t)(kvoff) * DH),                            \
                (AS3 void*)(&Ks[buf][0] + t * 8), 16, 0, 0);                             \
            __builtin_amdgcn_global_load_lds(                                            \
                (const AS1 void*)(Vg + (kvoff)),                                         \
                (AS3 void*)(&Vs[buf][0] + t * 8), 16, 0, 0);                             \
        } while (0)

    STAGE(0, 0);
    STAGE(1, KVBLK);
    asm volatile("s_waitcnt vmcnt(2)" ::: "memory");
    __builtin_amdgcn_s_barrier();

    const int NT = S_LEN / KVBLK;                // 32
    int cur = 0;
    for (int it = 0; it < NT; ++it) {
        if (it + 2 < NT) {
            int nb = cur + 2; if (nb >= 3) nb -= 3;
            STAGE(nb, (it + 2) * KVBLK);
        }

        const u16* Ksb = &Ks[cur][0];
        const u16* Vsb = &Vs[cur][0];

        // swapped QK^T with permuted K rows: s[j][r] = S^T[kv=f(j,g*4+r)][q=cl]
        f32x4 s[4];
        #pragma unroll
        for (int j = 0; j < 4; ++j) s[j] = zero;
        __builtin_amdgcn_s_setprio(1);
        #pragma unroll
        for (int j = 0; j < 4; ++j) {
            int row = ((j & 1) << 5) + ((cl >> 2) << 3) + ((j >> 1) << 2) + (cl & 3);
            bf16x8 k0 = *(const bf16x8*)&Ksb[row * 64 + ((g)     ^ kx) * 8];
            bf16x8 k1 = *(const bf16x8*)&Ksb[row * 64 + ((4 + g) ^ kx) * 8];
            s[j] = MFMA16(k0, qf0, s[j], 0, 0, 0);
            s[j] = MFMA16(k1, qf1, s[j], 0, 0, 0);
        }
        __builtin_amdgcn_s_setprio(0);

        // p = exp2(s); P stays in registers (lane's own PV A-fragment values)
        float p[4][4];
        #pragma unroll
        for (int j = 0; j < 4; ++j) {
            p[j][0] = __builtin_amdgcn_exp2f(s[j][0]);
            p[j][1] = __builtin_amdgcn_exp2f(s[j][1]);
            p[j][2] = __builtin_amdgcn_exp2f(s[j][2]);
            p[j][3] = __builtin_amdgcn_exp2f(s[j][3]);
        }
        bf16x8 pf[2];
        #pragma unroll
        for (int ks = 0; ks < 2; ++ks) {
            union { bf16x8 v8; uint32_t u[4]; } pk;
            pk.u[0] = pack_bf16(p[ks][0],     p[ks][1]);
            pk.u[1] = pack_bf16(p[ks][2],     p[ks][3]);
            pk.u[2] = pack_bf16(p[ks + 2][0], p[ks + 2][1]);
            pk.u[3] = pack_bf16(p[ks + 2][2], p[ks + 2][3]);
            pf[ks] = pk.v8;
        }

        // PV + row-sum: ones-MFMA accumulates rowsum[q] into sacc (matrix pipe)
        __builtin_amdgcn_s_setprio(1);
        sacc = MFMA16(pf[0], ones, sacc, 0, 0, 0);
        sacc = MFMA16(pf[1], ones, sacc, 0, 0, 0);
        #pragma unroll
        for (int tt = 0; tt < 4; ++tt) {
            int row = tt * 16 + cl;
            #pragma unroll
            for (int ks = 0; ks < 2; ++ks) {
                bf16x8 vf = *(const bf16x8*)&Vsb[row * 64 + ((ks * 4 + g) ^ vx) * 8];
                oacc[tt] = MFMA16(pf[ks], vf, oacc[tt], 0, 0, 0);
            }
        }
        __builtin_amdgcn_s_setprio(0);

        // counted-vmcnt barrier (T4): keep newest tile's loads in flight
        if (it + 2 < NT) {
            asm volatile("s_waitcnt vmcnt(2)\n\ts_barrier" ::: "memory");
        } else {
            asm volatile("s_waitcnt vmcnt(0)\n\ts_barrier" ::: "memory");
        }
        cur = (cur + 1 == 3) ? 0 : cur + 1;
    }
    #undef STAGE

    // sacc[r] = rowsum for q = g*4+r (replicated across cl) — no shuffles needed
    #pragma unroll
    for (int tt = 0; tt < 4; ++tt) {
        #pragma unroll
        for (int r = 0; r < 4; ++r) {
            int q = qw + g * 4 + r;
            float val = oacc[tt][r] / sacc[r];
            O[((size_t)b * S_LEN + q) * GN + h * DH + tt * 16 + cl] = f2bf(val);
        }
    }
}

// ---------------- launch ----------------
extern "C" void kernel_launch(void* const* d_in, const int* in_sizes, int n_in,
                              void* d_out, int out_size, void* d_ws, size_t ws_size,
                              hipStream_t stream) {
    const float* query = (const float*)d_in[0];
    const float* key   = (const float*)d_in[1];
    const float* value = (const float*)d_in[2];
    const float* Wq = (const float*)d_in[3];
    const float* bq = (const float*)d_in[4];
    const float* Wk = (const float*)d_in[5];
    const float* bk = (const float*)d_in[6];
    const float* Wv = (const float*)d_in[7];
    const float* bv = (const float*)d_in[8];
    const float* Wo = (const float*)d_in[9];
    const float* bo = (const float*)d_in[10];
    float* out = (float*)d_out;

    const float QSCALE = 0.125f * 1.4426950408889634f;

    u16* ws = (u16*)d_ws;
    const size_t MD = (size_t)GM * GN;   // 4,194,304
    const size_t WW = (size_t)GN * GK;   // 1,048,576
    u16* qbf = ws;
    u16* kbf = qbf + MD;
    u16* vbf = kbf + MD;
    u16* Wqb = vbf + MD;
    u16* Wkb = Wqb + WW;
    u16* Wvb = Wkb + WW;
    u16* Wob = Wvb + WW;
    u16* Qb  = Wob + WW;
    u16* Kbf = Qb  + MD;
    u16* Vtb = Kbf + MD;
    u16* Ob  = Vtb + MD;
    float* bqs = (float*)(Ob + MD);      // scaled bq (fp32, 1024)

    // 1) all conversions in one launch
    cvt_all_kernel<<<8196, 256, 0, stream>>>(query, key, value, Wq, Wk, Wv, Wo, bq,
                                             qbf, kbf, vbf, Wqb, Wkb, Wvb, Wob,
                                             bqs, QSCALE);

    // 2) Q/K/V projections (BK=32 2-phase dbuf + T1 XCD swizzle)
    proj_gemm<<<768, 256, 0, stream>>>(qbf, kbf, vbf, Wqb, Wkb, Wvb,
                                       bqs, bk, bv, Qb, Kbf, Vtb);

    // 3) flash attention (8 waves/block, 128 q-rows/block)
    dim3 gattn(2 * NH, S_LEN / 128);
    attn_kernel<<<gattn, 512, 0, stream>>>(Qb, Kbf, Vtb, Ob);

    // 4) output projection -> fp32 d_out (BK=32, XCD-swizzled — R13-exact)
    out_gemm<<<256, 256, 0, stream>>>(Ob, Wob, bo, out);
}

// Round 21
// 124.908 us; speedup vs baseline: 1.0417x; 1.0417x over previous
//
#include <hip/hip_runtime.h>
#include <hip/hip_bf16.h>
#include <stdint.h>

// MHA: B=2, S=2048, D=1024, H=16, Dh=64.
// cvt_all: fp32->bf16 for inputs+weights (one launch).
// proj GEMM (R19-exact): BK=32 2-phase dbuf, plain 2D grid (T1 harms here — 2x measured).
// out GEMM: BK=32 2-phase dbuf + T1 XCD swizzle.
// attn (R20): 8 waves x 16 q-rows, 3-buffer counted-vmcnt staging, permuted-K
//       swapped QK^T (P lane-local, no LDS roundtrip), no-max exp2 softmax,
//       row-sum via ones-MFMA.

typedef unsigned short u16;
typedef __attribute__((ext_vector_type(8))) short bf16x8;   // 8 bf16 = 4 VGPR
typedef __attribute__((ext_vector_type(4))) float f32x4;

#define MFMA16 __builtin_amdgcn_mfma_f32_16x16x32_bf16
#define AS1 __attribute__((address_space(1)))
#define AS3 __attribute__((address_space(3)))

#define GM 4096
#define GN 1024
#define GK 1024
#define S_LEN 2048
#define NH 16
#define DH 64
#define KVBLK 64

__device__ __forceinline__ u16 f2bf(float f) {
    union { float f; uint32_t u; } v; v.f = f;
    return (u16)((v.u + 0x7fffu + ((v.u >> 16) & 1u)) >> 16);
}

__device__ __forceinline__ uint32_t pack_bf16(float lo, float hi) {
    float2 t; t.x = lo; t.y = hi;
    __hip_bfloat162 h = __float22bfloat162_rn(t);
    return *(uint32_t*)&h;
}

// ---------------- fused fp32 -> bf16 convert for all 7 tensors + bq scale ----------------
__global__ __launch_bounds__(256) void cvt_all_kernel(
        const float* __restrict__ q, const float* __restrict__ k, const float* __restrict__ v,
        const float* __restrict__ Wq, const float* __restrict__ Wk,
        const float* __restrict__ Wv, const float* __restrict__ Wo,
        const float* __restrict__ bq,
        u16* __restrict__ qbf, u16* __restrict__ kbf, u16* __restrict__ vbf,
        u16* __restrict__ Wqb, u16* __restrict__ Wkb, u16* __restrict__ Wvb,
        u16* __restrict__ Wob, float* __restrict__ bqs, float qscale) {
    int bid = blockIdx.x;
    if (bid >= 8192) {                   // bq scale (fp32 passthrough)
        int i = (bid - 8192) * 256 + (int)threadIdx.x;
        if (i < GN) bqs[i] = bq[i] * qscale;
        return;
    }
    const float* src; u16* dst; float scale = 1.f; int off;
    if      (bid < 2048) { src = q;  dst = qbf; off = bid; }
    else if (bid < 4096) { src = k;  dst = kbf; off = bid - 2048; }
    else if (bid < 6144) { src = v;  dst = vbf; off = bid - 4096; }
    else if (bid < 6656) { src = Wq; dst = Wqb; off = bid - 6144; scale = qscale; }
    else if (bid < 7168) { src = Wk; dst = Wkb; off = bid - 6656; }
    else if (bid < 7680) { src = Wv; dst = Wvb; off = bid - 7168; }
    else                 { src = Wo; dst = Wob; off = bid - 7680; }
    size_t i = (size_t)off * 256 + threadIdx.x;
    const f32x4* s = (const f32x4*)src + i * 2;
    f32x4 a = s[0], b = s[1];
    union { bf16x8 v8; u16 u[8]; } o;
    o.u[0] = f2bf(a[0] * scale); o.u[1] = f2bf(a[1] * scale);
    o.u[2] = f2bf(a[2] * scale); o.u[3] = f2bf(a[3] * scale);
    o.u[4] = f2bf(b[0] * scale); o.u[5] = f2bf(b[1] * scale);
    o.u[6] = f2bf(b[2] * scale); o.u[7] = f2bf(b[3] * scale);
    *(bf16x8*)(dst + i * 8) = o.v8;
}

// ---------------- 128x128-tile bf16 GEMM core (R13-exact), templated K-depth ----------------
template<int BK>
__device__ __forceinline__ void gemm_core(const u16* __restrict__ A,
                                          const u16* __restrict__ W,
                                          const float* __restrict__ bias,
                                          void* __restrict__ Cout, int mode,
                                          u16* As, u16* Bs,
                                          int mbase, int nbase) {
    const int t  = threadIdx.x;
    const int l  = t & 63;
    const int w  = t >> 6;
    const int wr = w >> 1, wc = w & 1;           // 2x2 wave grid
    const int cl = l & 15, g = l >> 4;
    constexpr int CPR  = BK / 8;                 // 16B chunks per row
    constexpr int NCH  = 128 * CPR / 256;        // chunk-loop count per tensor
    constexpr int TE   = 128 * BK;               // tile elems (u16)

    f32x4 acc[4][4];
    f32x4 zero = {0.f, 0.f, 0.f, 0.f};
    #pragma unroll
    for (int i = 0; i < 4; ++i)
        #pragma unroll
        for (int j = 0; j < 4; ++j) acc[i][j] = zero;

    auto skey = [](int row) -> int {
        if constexpr (BK == 64) return row & 7;
        else                    return (row >> 1) & 3;
    };

    auto stage = [&](int buf, int kt) {
        #pragma unroll
        for (int r = 0; r < NCH; ++r) {
            int c = r * 256 + t;
            int row = c / CPR;
            int c8 = (c % CPR) ^ skey(row);
            __builtin_amdgcn_global_load_lds(
                (const AS1 void*)(A + (size_t)(mbase + row) * GK + kt + c8 * 8),
                (AS3 void*)(As + buf * TE + c * 8), 16, 0, 0);
            __builtin_amdgcn_global_load_lds(
                (const AS1 void*)(W + (size_t)(nbase + row) * GK + kt + c8 * 8),
                (AS3 void*)(Bs + buf * TE + c * 8), 16, 0, 0);
        }
    };

    stage(0, 0);
    __syncthreads();

    int cur = 0;
    for (int kt = 0; kt < GK; kt += BK) {
        if (kt + BK < GK) stage(cur ^ 1, kt + BK);   // prefetch next tile

        const u16* Asb = As + cur * TE;
        const u16* Bsb = Bs + cur * TE;
        #pragma unroll
        for (int ks = 0; ks < BK / 32; ++ks) {
            bf16x8 af[4], bfr[4];
            #pragma unroll
            for (int mi = 0; mi < 4; ++mi) {
                int row = wr * 64 + mi * 16 + cl;
                af[mi] = *(const bf16x8*)&Asb[row * BK + ((ks * 4 + g) ^ skey(row)) * 8];
            }
            #pragma unroll
            for (int nj = 0; nj < 4; ++nj) {
                int row = wc * 64 + nj * 16 + cl;
                bfr[nj] = *(const bf16x8*)&Bsb[row * BK + ((ks * 4 + g) ^ skey(row)) * 8];
            }
            #pragma unroll
            for (int mi = 0; mi < 4; ++mi)
                #pragma unroll
                for (int nj = 0; nj < 4; ++nj)
                    acc[mi][nj] = MFMA16(af[mi], bfr[nj], acc[mi][nj], 0, 0, 0);
        }
        __syncthreads();
        cur ^= 1;
    }

    // epilogue: C/D layout col = lane&15, row = (lane>>4)*4 + reg (m89-verified)
    #pragma unroll
    for (int mi = 0; mi < 4; ++mi) {
        #pragma unroll
        for (int nj = 0; nj < 4; ++nj) {
            int n = nbase + wc * 64 + nj * 16 + cl;
            float bv = bias[n];
            #pragma unroll
            for (int r = 0; r < 4; ++r) {
                int m = mbase + wr * 64 + mi * 16 + g * 4 + r;
                float vv = acc[mi][nj][r] + bv;
                if (mode == 2) {
                    ((float*)Cout)[(size_t)m * GN + n] = vv;
                } else {
                    int b = m >> 11, s = m & 2047;
                    int hh = n >> 6, dh = n & 63;
                    if (mode == 0)       // [B,H,S,Dh]
                        ((u16*)Cout)[(((size_t)(b * NH + hh)) * S_LEN + s) * DH + dh] = f2bf(vv);
                    else                 // [B,H,Dh,S]  (V transposed)
                        ((u16*)Cout)[(((size_t)(b * NH + hh)) * DH + dh) * S_LEN + s] = f2bf(vv);
                }
            }
        }
    }
}

__global__ __launch_bounds__(256) void proj_gemm(
        const u16* __restrict__ qbf, const u16* __restrict__ kbf, const u16* __restrict__ vbf,
        const u16* __restrict__ Wqb, const u16* __restrict__ Wkb, const u16* __restrict__ Wvb,
        const float* __restrict__ bq, const float* __restrict__ bk, const float* __restrict__ bv,
        u16* __restrict__ Qb, u16* __restrict__ Kb, u16* __restrict__ Vtb) {
    __shared__ u16 As[2 * 128 * 32];     // 16KB
    __shared__ u16 Bs[2 * 128 * 32];     // 16KB  -> 32KB total, 3 blocks/CU
    int z = blockIdx.z;
    const u16* A   = (z == 0) ? qbf : (z == 1) ? kbf : vbf;
    const u16* W   = (z == 0) ? Wqb : (z == 1) ? Wkb : Wvb;
    const float* b = (z == 0) ? bq  : (z == 1) ? bk  : bv;
    u16* C         = (z == 0) ? Qb  : (z == 1) ? Kb  : Vtb;
    gemm_core<32>(A, W, b, (void*)C, (z == 2) ? 1 : 0, As, Bs,
                  blockIdx.y * 128, blockIdx.x * 128);
}

__global__ __launch_bounds__(256) void out_gemm(const u16* __restrict__ A,
                                                const u16* __restrict__ W,
                                                const float* __restrict__ bias,
                                                float* __restrict__ C) {
    __shared__ u16 As[2 * 128 * 32];
    __shared__ u16 Bs[2 * 128 * 32];
    int bid = blockIdx.x;                        // 256 blocks, 256%8==0
    int lid = (bid & 7) * 32 + (bid >> 3);
    int x = lid & 7, y = lid >> 3;
    gemm_core<32>(A, W, bias, (void*)C, 2, As, Bs, y * 128, x * 128);
}

// ---------------- flash attention: permuted-K swapped QK^T, ones-MFMA row-sum ----------------
__global__ __launch_bounds__(512, 4) void attn_kernel(const u16* __restrict__ Q,
                                                      const u16* __restrict__ Kb,
                                                      const u16* __restrict__ Vt,
                                                      u16* __restrict__ O) {
    __shared__ u16 Ks[3][KVBLK * 64];            // 8KB each
    __shared__ u16 Vs[3][KVBLK * 64];            // 8KB each  -> 48KB total

    const int t = threadIdx.x, l = t & 63, w = t >> 6;
    const int cl = l & 15, g = l >> 4;
    const int bh = blockIdx.x;                   // 0..31
    const int b = bh >> 4, h = bh & 15;
    const int qw = blockIdx.y * 128 + w * 16;    // this wave's q-row base

    const u16* Qp = Q  + ((size_t)bh * S_LEN + qw) * DH;
    const u16* Kp = Kb + (size_t)bh * S_LEN * DH;
    const u16* Vp = Vt + (size_t)bh * DH * S_LEN;

    // Q fragment (q = cl, d = (lane>>4)*8+e) — MFMA B-operand of swapped QK^T
    bf16x8 qf0 = *(const bf16x8*)(Qp + (size_t)cl * DH + g * 8);
    bf16x8 qf1 = *(const bf16x8*)(Qp + (size_t)cl * DH + 32 + g * 8);

    f32x4 oacc[4];
    f32x4 zero = {0.f, 0.f, 0.f, 0.f};
    #pragma unroll
    for (int tt = 0; tt < 4; ++tt) oacc[tt] = zero;
    f32x4 sacc = zero;                           // row-sum accumulator (ones-MFMA)

    bf16x8 ones;
    #pragma unroll
    for (int e = 0; e < 8; ++e) ones[e] = (short)0x3F80;   // bf16 1.0

    // read-side swizzle keys (storage key(row)=(row&3)|((row>>3)&1)<<2)
    const int kx = (cl & 3) | (((cl >> 2) & 1) << 2);
    const int vx = (cl & 3) | (((cl >> 3) & 1) << 2);

    // staging geometry: 512 threads x one 16B chunk per tensor.
    const int srow = t >> 3;
    const int sc8  = (t & 7) ^ ((srow & 3) | (((srow >> 3) & 1) << 2));
    const u16* Kg = Kp + (size_t)srow * DH + sc8 * 8;
    const u16* Vg = Vp + (size_t)srow * S_LEN + sc8 * 8;

    #define STAGE(buf, kvoff)                                                            \
        do {                                                                             \
            __builtin_amdgcn_global_load_lds(                                            \
                (const AS1 void*)(Kg + (size_t)(kvoff) * DH),                            \
                (AS3 void*)(&Ks[buf][0] + t * 8), 16, 0, 0);                             \
            __builtin_amdgcn_global_load_lds(                                            \
                (const AS1 void*)(Vg + (kvoff)),                                         \
                (AS3 void*)(&Vs[buf][0] + t * 8), 16, 0, 0);                             \
        } while (0)

    STAGE(0, 0);
    STAGE(1, KVBLK);
    asm volatile("s_waitcnt vmcnt(2)" ::: "memory");
    __builtin_amdgcn_s_barrier();

    const int NT = S_LEN / KVBLK;                // 32
    int cur = 0;
    for (int it = 0; it < NT; ++it) {
        if (it + 2 < NT) {
            int nb = cur + 2; if (nb >= 3) nb -= 3;
            STAGE(nb, (it + 2) * KVBLK);
        }

        const u16* Ksb = &Ks[cur][0];
        const u16* Vsb = &Vs[cur][0];

        // swapped QK^T with permuted K rows: s[j][r] = S^T[kv=f(j,g*4+r)][q=cl]
        f32x4 s[4];
        #pragma unroll
        for (int j = 0; j < 4; ++j) s[j] = zero;
        __builtin_amdgcn_s_setprio(1);
        #pragma unroll
        for (int j = 0; j < 4; ++j) {
            int row = ((j & 1) << 5) + ((cl >> 2) << 3) + ((j >> 1) << 2) + (cl & 3);
            bf16x8 k0 = *(const bf16x8*)&Ksb[row * 64 + ((g)     ^ kx) * 8];
            bf16x8 k1 = *(const bf16x8*)&Ksb[row * 64 + ((4 + g) ^ kx) * 8];
            s[j] = MFMA16(k0, qf0, s[j], 0, 0, 0);
            s[j] = MFMA16(k1, qf1, s[j], 0, 0, 0);
        }
        __builtin_amdgcn_s_setprio(0);

        // p = exp2(s); P stays in registers (lane's own PV A-fragment values)
        float p[4][4];
        #pragma unroll
        for (int j = 0; j < 4; ++j) {
            p[j][0] = __builtin_amdgcn_exp2f(s[j][0]);
            p[j][1] = __builtin_amdgcn_exp2f(s[j][1]);
            p[j][2] = __builtin_amdgcn_exp2f(s[j][2]);
            p[j][3] = __builtin_amdgcn_exp2f(s[j][3]);
        }
        bf16x8 pf[2];
        #pragma unroll
        for (int ks = 0; ks < 2; ++ks) {
            union { bf16x8 v8; uint32_t u[4]; } pk;
            pk.u[0] = pack_bf16(p[ks][0],     p[ks][1]);
            pk.u[1] = pack_bf16(p[ks][2],     p[ks][3]);
            pk.u[2] = pack_bf16(p[ks + 2][0], p[ks + 2][1]);
            pk.u[3] = pack_bf16(p[ks + 2][2], p[ks + 2][3]);
            pf[ks] = pk.v8;
        }

        // PV + row-sum: ones-MFMA accumulates rowsum[q] into sacc (matrix pipe)
        __builtin_amdgcn_s_setprio(1);
        sacc = MFMA16(pf[0], ones, sacc, 0, 0, 0);
        sacc = MFMA16(pf[1], ones, sacc, 0, 0, 0);
        #pragma unroll
        for (int tt = 0; tt < 4; ++tt) {
            int row = tt * 16 + cl;
            #pragma unroll
            for (int ks = 0; ks < 2; ++ks) {
                bf16x8 vf = *(const bf16x8*)&Vsb[row * 64 + ((ks * 4 + g) ^ vx) * 8];
                oacc[tt] = MFMA16(pf[ks], vf, oacc[tt], 0, 0, 0);
            }
        }
        __builtin_amdgcn_s_setprio(0);

        // counted-vmcnt barrier (T4): keep newest tile's loads in flight
        if (it + 2 < NT) {
            asm volatile("s_waitcnt vmcnt(2)\n\ts_barrier" ::: "memory");
        } else {
            asm volatile("s_waitcnt vmcnt(0)\n\ts_barrier" ::: "memory");
        }
        cur = (cur + 1 == 3) ? 0 : cur + 1;
    }
    #undef STAGE

    // sacc[r] = rowsum for q = g*4+r (replicated across cl) — no shuffles needed
    #pragma unroll
    for (int tt = 0; tt < 4; ++tt) {
        #pragma unroll
        for (int r = 0; r < 4; ++r) {
            int q = qw + g * 4 + r;
            float val = oacc[tt][r] / sacc[r];
            O[((size_t)b * S_LEN + q) * GN + h * DH + tt * 16 + cl] = f2bf(val);
        }
    }
}

// ---------------- launch ----------------
extern "C" void kernel_launch(void* const* d_in, const int* in_sizes, int n_in,
                              void* d_out, int out_size, void* d_ws, size_t ws_size,
                              hipStream_t stream) {
    const float* query = (const float*)d_in[0];
    const float* key   = (const float*)d_in[1];
    const float* value = (const float*)d_in[2];
    const float* Wq = (const float*)d_in[3];
    const float* bq = (const float*)d_in[4];
    const float* Wk = (const float*)d_in[5];
    const float* bk = (const float*)d_in[6];
    const float* Wv = (const float*)d_in[7];
    const float* bv = (const float*)d_in[8];
    const float* Wo = (const float*)d_in[9];
    const float* bo = (const float*)d_in[10];
    float* out = (float*)d_out;

    const float QSCALE = 0.125f * 1.4426950408889634f;

    u16* ws = (u16*)d_ws;
    const size_t MD = (size_t)GM * GN;   // 4,194,304
    const size_t WW = (size_t)GN * GK;   // 1,048,576
    u16* qbf = ws;
    u16* kbf = qbf + MD;
    u16* vbf = kbf + MD;
    u16* Wqb = vbf + MD;
    u16* Wkb = Wqb + WW;
    u16* Wvb = Wkb + WW;
    u16* Wob = Wvb + WW;
    u16* Qb  = Wob + WW;
    u16* Kbf = Qb  + MD;
    u16* Vtb = Kbf + MD;
    u16* Ob  = Vtb + MD;
    float* bqs = (float*)(Ob + MD);      // scaled bq (fp32, 1024)

    // 1) all conversions in one launch
    cvt_all_kernel<<<8196, 256, 0, stream>>>(query, key, value, Wq, Wk, Wv, Wo, bq,
                                             qbf, kbf, vbf, Wqb, Wkb, Wvb, Wob,
                                             bqs, QSCALE);

    // 2) Q/K/V projections (BK=32 2-phase dbuf, plain 2D grid — R19-exact)
    dim3 gproj(GN / 128, GM / 128, 3);
    proj_gemm<<<gproj, 256, 0, stream>>>(qbf, kbf, vbf, Wqb, Wkb, Wvb,
                                         bqs, bk, bv, Qb, Kbf, Vtb);

    // 3) flash attention (8 waves/block, 128 q-rows/block)
    dim3 gattn(2 * NH, S_LEN / 128);
    attn_kernel<<<gattn, 512, 0, stream>>>(Qb, Kbf, Vtb, Ob);

    // 4) output projection -> fp32 d_out (BK=32, XCD-swizzled)
    out_gemm<<<256, 256, 0, stream>>>(Ob, Wob, bo, out);
}